// Round 10
// baseline (880.808 us; speedup 1.0000x reference)
//
#include <hip/hip_runtime.h>
#include <hip/hip_bf16.h>
#include <stdint.h>

#define NN 10000
#define EE 50000
#define MPAD 50176  // EE padded to multiple of 128

typedef __hip_bfloat16 bf16_t;
typedef __attribute__((ext_vector_type(8))) short bf16x8;
typedef __attribute__((ext_vector_type(4))) float f32x4;

__device__ __forceinline__ float bf2f(unsigned short u) {
  union { unsigned int i; float f; } v; v.i = ((unsigned int)u) << 16; return v.f;
}

__device__ __forceinline__ void async_load16(const void* g, void* lds) {
  __builtin_amdgcn_global_load_lds((const __attribute__((address_space(1))) uint32_t*)g,
                                   (__attribute__((address_space(3))) uint32_t*)lds,
                                   16, 0, 0);
}

#define MFMA16(a, b, c) __builtin_amdgcn_mfma_f32_16x16x32_bf16(a, b, c, 0, 0, 0)

// C[M][N] = act(A[M][K] @ Bt[N][K]^T + bias[N]); bf16 row-major, M,N mult 128, K mult 64.
// Proven r2 structure: 944 TF, MfmaUtil 42%, 0 bank conflicts. DO NOT TOUCH without A/B.
template <bool RELU>
__global__ __launch_bounds__(256, 2)
void gemm_bt(const bf16_t* __restrict__ A, const bf16_t* __restrict__ Bt,
             const float* __restrict__ bias, bf16_t* __restrict__ C,
             int N, int K) {
  __shared__ __align__(16) bf16_t As[128 * 64];
  __shared__ __align__(16) bf16_t Bs[128 * 64];

  const int t = threadIdx.x;
  const int lane = t & 63;
  const int wave = t >> 6;
  const int nt = N >> 7;
  const int bm = blockIdx.x / nt;
  const int bn = blockIdx.x % nt;
  const size_t aRowBase = (size_t)bm << 7;
  const size_t bRowBase = (size_t)bn << 7;

  const int wrBase = (wave >> 1) << 6;
  const int wcBase = (wave & 1) << 6;
  const int lo = lane & 15;
  const int hi = lane >> 4;

  f32x4 acc[4][4] = {};

  const int stg_r = t >> 3;
  const int stg_s = t & 7;
  char* AsB = (char*)As;
  char* BsB = (char*)Bs;

  const int nkt = K >> 6;
  for (int kt = 0; kt < nkt; ++kt) {
    __syncthreads();
    #pragma unroll
    for (int it = 0; it < 4; ++it) {
      const int r = (it << 5) + stg_r;
      const int ls = (stg_s ^ (r & 7)) << 3;
      async_load16(A + (aRowBase + r) * K + (kt << 6) + ls,
                   AsB + (it << 12) + (wave << 10));
      async_load16(Bt + (bRowBase + r) * K + (kt << 6) + ls,
                   BsB + (it << 12) + (wave << 10));
    }
    __syncthreads();
    #pragma unroll
    for (int ks = 0; ks < 2; ++ks) {
      bf16x8 af[4], bfr[4];
      #pragma unroll
      for (int m = 0; m < 4; ++m) {
        const int row = wrBase + (m << 4) + lo;
        const int ps = ((ks << 2) + hi) ^ (row & 7);
        af[m] = *(const bf16x8*)(AsB + (row << 7) + (ps << 4));
      }
      #pragma unroll
      for (int n = 0; n < 4; ++n) {
        const int row = wcBase + (n << 4) + lo;
        const int ps = ((ks << 2) + hi) ^ (row & 7);
        bfr[n] = *(const bf16x8*)(BsB + (row << 7) + (ps << 4));
      }
      #pragma unroll
      for (int m = 0; m < 4; ++m)
        #pragma unroll
        for (int n = 0; n < 4; ++n)
          acc[m][n] = MFMA16(af[m], bfr[n], acc[m][n]);
    }
  }

  #pragma unroll
  for (int m = 0; m < 4; ++m) {
    #pragma unroll
    for (int n = 0; n < 4; ++n) {
      const int col = (bn << 7) + wcBase + (n << 4) + lo;
      const float bv = bias[col];
      #pragma unroll
      for (int j = 0; j < 4; ++j) {
        const int row = (bm << 7) + wrBase + (m << 4) + (hi << 2) + j;
        float v = acc[m][n][j] + bv;
        if (RELU) v = fmaxf(v, 0.0f);
        C[(size_t)row * N + col] = __float2bfloat16(v);
      }
    }
  }
}

// Fused k3 GEMM + per-edge matvec + atomic scatter, EXACT gemm_bt tile geometry
// (r9 lesson: 64-edge tile = 2/3 MFMA density = 618 TF; gemm_bt 128x128 = 944 TF).
// Block: 128 edges (mt = blockIdx.x) x 1024 W-cols (s = blockIdx.y; col-tiles
// bn = s*8+ct, ct 0..7 of 128 cols). Per ct: full-K (8 kt) gemm_bt loop -> acc[4][4];
// fold into msg[4][4][4] (i = 2*bn+wcb, ONE h value/thread/ct from LDS h-slice;
// bias full per ct since full-K). s-major dispatch (y-grid) -> each XCD's L2 holds
// one 1MB Bt slice (r9: round-robin thrashed all 4MB -> 290MB re-fetch).
// Regs: acc 64 (AGPR) + msg 64 + frags/addr ~50 -> ~180 unified, 2 waves/SIMD, no cap.
__global__ __launch_bounds__(256, 2)
void k3msgG2(const bf16_t* __restrict__ A, const bf16_t* __restrict__ Bt,
             const float* __restrict__ b3, const float* __restrict__ h,
             const int* __restrict__ ei, float* __restrict__ agg,
             int e0, int ne) {
  __shared__ __align__(16) bf16_t As[128 * 64];   // 16KB
  __shared__ __align__(16) bf16_t Bs[128 * 64];   // 16KB
  __shared__ __align__(16) float HL[128 * 20];    // 10KB: h[row][s*16..+15], stride 20

  const int t = threadIdx.x, lane = t & 63, wave = t >> 6;
  const int wrBase = (wave >> 1) << 6;  // 0/64 (edge rows)
  const int wcb = wave & 1;             // col-half -> i parity
  const int wcBase = wcb << 6;          // 0/64 (cols)
  const int lo = lane & 15, hi = lane >> 4;
  const int mt = blockIdx.x;
  const int s = blockIdx.y;
  const int aRow0 = mt << 7;

  // gather h slice: thread t -> row t>>1, 8 floats at (t&1)*8 (cols s*16..+15)
  {
    const int row = t >> 1, c8 = (t & 1) << 3;
    const int rg = aRow0 + row;
    float4 h0 = make_float4(0.f, 0.f, 0.f, 0.f), h1 = h0;
    if (rg < ne) {
      const unsigned sv = (unsigned)ei[e0 + rg];
      if (sv < NN) {
        const float* hp = h + ((size_t)sv << 6) + (s << 4) + c8;
        h0 = *(const float4*)hp;
        h1 = *(const float4*)(hp + 4);
      }
    }
    *(float4*)(HL + row * 20 + c8) = h0;
    *(float4*)(HL + row * 20 + c8 + 4) = h1;
  }

  const int stg_r = t >> 3;
  const int stg_s = t & 7;
  char* AsB = (char*)As;
  char* BsB = (char*)Bs;

  float msg[4][4][4] = {};  // [m][nf][j]

  for (int ct = 0; ct < 8; ++ct) {
    const int bn = (s << 3) + ct;
    f32x4 acc[4][4] = {};
    for (int kt = 0; kt < 8; ++kt) {
      __syncthreads();
      #pragma unroll
      for (int it = 0; it < 4; ++it) {
        const int r = (it << 5) + stg_r;
        const int ls = (stg_s ^ (r & 7)) << 3;
        async_load16(A + (size_t)(aRow0 + r) * 512 + (kt << 6) + ls,
                     AsB + (it << 12) + (wave << 10));
        async_load16(Bt + (size_t)((bn << 7) + r) * 512 + (kt << 6) + ls,
                     BsB + (it << 12) + (wave << 10));
      }
      __syncthreads();
      #pragma unroll
      for (int ks = 0; ks < 2; ++ks) {
        bf16x8 af[4], bfr[4];
        #pragma unroll
        for (int m = 0; m < 4; ++m) {
          const int row = wrBase + (m << 4) + lo;
          const int ps = ((ks << 2) + hi) ^ (row & 7);
          af[m] = *(const bf16x8*)(AsB + (row << 7) + (ps << 4));
        }
        #pragma unroll
        for (int n = 0; n < 4; ++n) {
          const int cl = wcBase + (n << 4) + lo;
          const int ps = ((ks << 2) + hi) ^ (cl & 7);
          bfr[n] = *(const bf16x8*)(BsB + (cl << 7) + (ps << 4));
        }
        #pragma unroll
        for (int m = 0; m < 4; ++m)
          #pragma unroll
          for (int n = 0; n < 4; ++n)
            acc[m][n] = MFMA16(af[m], bfr[n], acc[m][n]);
      }
    }
    // fold: i = 2*bn+wcb -> iloc = 2*ct+wcb; o = nf*16+lo; bias full (full-K acc)
    const int iloc = (ct << 1) + wcb;
    float bv[4];
    #pragma unroll
    for (int nf = 0; nf < 4; ++nf)
      bv[nf] = b3[(bn << 7) + wcBase + (nf << 4) + lo];
    #pragma unroll
    for (int m = 0; m < 4; ++m)
      #pragma unroll
      for (int j = 0; j < 4; ++j) {
        const int row = wrBase + (m << 4) + (hi << 2) + j;
        const float hv = HL[row * 20 + iloc];
        #pragma unroll
        for (int nf = 0; nf < 4; ++nf)
          msg[m][nf][j] = fmaf(hv, acc[m][nf][j] + bv[nf], msg[m][nf][j]);
      }
  }

  // scatter (wcb halves hold complementary i-partials for the same o)
  #pragma unroll
  for (int m = 0; m < 4; ++m)
    #pragma unroll
    for (int j = 0; j < 4; ++j) {
      const int rg = aRow0 + wrBase + (m << 4) + (hi << 2) + j;
      if (rg < ne) {
        const unsigned dst = (unsigned)ei[EE + e0 + rg];
        if (dst < NN) {
          float* ag = agg + ((size_t)dst << 6);
          #pragma unroll
          for (int nf = 0; nf < 4; ++nf)
            atomicAdd(ag + (nf << 4) + lo, msg[m][nf][j]);
        }
      }
    }
}

// wt[n*K + k] = bf16(w[k*N + n])  (transpose + cast)
__global__ void convert_t(const float* __restrict__ w, bf16_t* __restrict__ wt,
                          int K, int N) {
  int idx = blockIdx.x * 256 + threadIdx.x;
  if (idx >= K * N) return;
  int n = idx / K, k = idx - n * K;
  wt[idx] = __float2bfloat16(w[(size_t)k * N + n]);
}

__global__ void fc1_kernel(const float* __restrict__ x, const float* __restrict__ w,
                           const float* __restrict__ b, float* __restrict__ h) {
  int idx = blockIdx.x * 256 + threadIdx.x;
  if (idx >= NN * 64) return;
  int n = idx >> 6, j = idx & 63;
  h[idx] = fmaf(x[n], w[j], b[j]);
}

__global__ void deg_kernel(const int* __restrict__ ei, float* __restrict__ deg) {
  int e = blockIdx.x * 256 + threadIdx.x;
  if (e < EE) {
    unsigned d = (unsigned)ei[EE + e];
    if (d < NN) atomicAdd(&deg[d], 1.0f);
  }
}

// e1[el][0:256] = relu(attr[e0+el] @ k1_w + k1_b), zeros for rows >= ne
__global__ void k1_kernel(const float* __restrict__ attr, const float* __restrict__ w,
                          const float* __restrict__ b, bf16_t* __restrict__ e1,
                          int e0, int ne) {
  const int el = blockIdx.x;
  const int j = threadIdx.x;
  __shared__ float a[6];
  if (el < ne && j < 6) a[j] = attr[(size_t)(e0 + el) * 6 + j];
  __syncthreads();
  float v = 0.0f;
  if (el < ne) {
    v = b[j];
    #pragma unroll
    for (int i = 0; i < 6; ++i) v = fmaf(a[i], w[i * 256 + j], v);
    v = fmaxf(v, 0.0f);
  }
  e1[(size_t)el * 256 + j] = __float2bfloat16(v);
}

// per-edge matvec from cached W (bf16): msg[o] = sum_i h[src][i]*W[el][i*64+o]
__global__ __launch_bounds__(256)
void msg_kernel(const float* __restrict__ h, const bf16_t* __restrict__ W,
                const int* __restrict__ ei, float* __restrict__ agg,
                int e0, int ne) {
  const int el = blockIdx.x * 4 + (threadIdx.x >> 6);
  if (el >= ne) return;
  const int e = e0 + el;
  const int lane = threadIdx.x & 63;
  const int g = lane >> 4, c = lane & 15;
  const unsigned src = (unsigned)ei[e], dst = (unsigned)ei[EE + e];
  if (src >= NN || dst >= NN) return;
  const float hv = h[src * 64 + lane];
  const unsigned short* We = (const unsigned short*)(W + (size_t)el * 4096);
  float a0 = 0, a1 = 0, a2 = 0, a3 = 0;
  #pragma unroll
  for (int i0 = 0; i0 < 64; i0 += 4) {
    const int i = i0 + g;
    const float hs = __shfl(hv, i);
    ushort4 wv = *(const ushort4*)(We + i * 64 + c * 4);
    a0 = fmaf(hs, bf2f(wv.x), a0);
    a1 = fmaf(hs, bf2f(wv.y), a1);
    a2 = fmaf(hs, bf2f(wv.z), a2);
    a3 = fmaf(hs, bf2f(wv.w), a3);
  }
  a0 += __shfl_xor(a0, 16); a0 += __shfl_xor(a0, 32);
  a1 += __shfl_xor(a1, 16); a1 += __shfl_xor(a1, 32);
  a2 += __shfl_xor(a2, 16); a2 += __shfl_xor(a2, 32);
  a3 += __shfl_xor(a3, 16); a3 += __shfl_xor(a3, 32);
  if (g == 0) {
    float* ag = agg + (size_t)dst * 64 + c * 4;
    atomicAdd(ag + 0, a0);
    atomicAdd(ag + 1, a1);
    atomicAdd(ag + 2, a2);
    atomicAdd(ag + 3, a3);
  }
}

// h_new = relu(agg/deg + h @ root + gcn_b)
__global__ __launch_bounds__(256)
void update_kernel(const float* __restrict__ h, const float* __restrict__ agg,
                   const float* __restrict__ deg, const float* __restrict__ root,
                   const float* __restrict__ gb, float* __restrict__ hn) {
  const int n = blockIdx.x * 4 + (threadIdx.x >> 6);
  if (n >= NN) return;
  const int lane = threadIdx.x & 63;
  const float hv = h[n * 64 + lane];
  float acc = 0.0f;
  #pragma unroll
  for (int i = 0; i < 64; ++i)
    acc = fmaf(__shfl(hv, i), root[i * 64 + lane], acc);
  const float d = fmaxf(deg[n], 1.0f);
  const float v = agg[n * 64 + lane] / d + acc + gb[lane];
  hn[n * 64 + lane] = fmaxf(v, 0.0f);
}

__global__ __launch_bounds__(256)
void fc2_kernel(const float* __restrict__ h, const float* __restrict__ w,
                const float* __restrict__ b, float* __restrict__ out) {
  const int n = blockIdx.x * 4 + (threadIdx.x >> 6);
  if (n >= NN) return;
  const int lane = threadIdx.x & 63;
  float v = h[n * 64 + lane] * w[lane];
  #pragma unroll
  for (int off = 32; off > 0; off >>= 1) v += __shfl_xor(v, off);
  if (lane == 0) out[n] = v + b[0];
}

extern "C" void kernel_launch(void* const* d_in, const int* in_sizes, int n_in,
                              void* d_out, int out_size, void* d_ws, size_t ws_size,
                              hipStream_t stream) {
  const float* x     = (const float*)d_in[0];
  const int*   ei    = (const int*)d_in[1];
  const float* attr  = (const float*)d_in[2];
  const float* fc1_w = (const float*)d_in[3];
  const float* fc1_b = (const float*)d_in[4];
  const float* k1_w  = (const float*)d_in[5];
  const float* k1_b  = (const float*)d_in[6];
  const float* k2_w  = (const float*)d_in[7];
  const float* k2_b  = (const float*)d_in[8];
  const float* k3_w  = (const float*)d_in[9];
  const float* k3_b  = (const float*)d_in[10];
  const float* root  = (const float*)d_in[11];
  const float* gcn_b = (const float*)d_in[12];
  const float* fc2_w = (const float*)d_in[13];
  const float* fc2_b = (const float*)d_in[14];
  float* out = (float*)d_out;
  (void)in_sizes; (void)n_in; (void)out_size;

  char* ws = (char*)d_ws;
  size_t off = 0;
  auto take = [&](size_t bytes) -> char* {
    char* p = ws + off;
    off += (bytes + 255) & ~(size_t)255;
    return p;
  };
  // fixed small buffers (~12.2 MB)
  bf16_t* k2wt = (bf16_t*)take((size_t)512 * 256 * 2);
  bf16_t* k3wt = (bf16_t*)take((size_t)4096 * 512 * 2);
  float*  hA   = (float*)take((size_t)NN * 64 * 4);
  float*  hB   = (float*)take((size_t)NN * 64 * 4);
  float*  agg  = (float*)take((size_t)NN * 64 * 4);
  float*  deg  = (float*)take((size_t)NN * 4);

  // e2 for all edges (51.4 MB); remaining region = e1 (transient) then Wcache
  bf16_t* e2full = (bf16_t*)take((size_t)MPAD * 512 * 2);
  size_t rem = (ws_size > off + 1024) ? ws_size - off - 1024 : 0;
  int Nc = (int)((rem / 8192) / 128) * 128;  // cached edges, mult of 128
  if (Nc > 49920) Nc = 49920;  // keep Te >= 80 (never let Te < 0)
  if (Nc < 0) Nc = 0;
  size_t e1B = (size_t)MPAD * 256 * 2;  // 25.7 MB
  size_t regionB = (size_t)Nc * 8192;
  if (regionB < e1B) regionB = e1B;
  char* region = take(regionB);
  bf16_t* Wcache = (bf16_t*)region;
  bf16_t* e1 = (bf16_t*)region;  // dead after k2; overwritten by Wcache fill

  const int Te = EE - Nc;                // tail edges (fused per layer)
  const int Mt128 = (Te + 127) & ~127;   // padded to 128 (Nc + Mt128 <= 50048 <= MPAD)

  // weight transposes + casts
  convert_t<<<(512 * 256 + 255) / 256, 256, 0, stream>>>(k2_w, k2wt, 256, 512);
  convert_t<<<(4096 * 512 + 255) / 256, 256, 0, stream>>>(k3_w, k3wt, 512, 4096);

  // h0 = x @ fc1_w + fc1_b
  fc1_kernel<<<(NN * 64 + 255) / 256, 256, 0, stream>>>(x, fc1_w, fc1_b, hA);

  // in-degree
  hipMemsetAsync(deg, 0, NN * 4, stream);
  deg_kernel<<<(EE + 255) / 256, 256, 0, stream>>>(ei, deg);

  // edge MLP front (full): k1 -> e1, k2 -> e2full
  k1_kernel<<<MPAD, 256, 0, stream>>>(attr, k1_w, k1_b, e1, 0, EE);
  gemm_bt<true><<<(MPAD >> 7) * 4, 256, 0, stream>>>(e1, k2wt, k2_b, e2full, 512, 256);

  // W cache fill (h-independent, once): proven 944-TF GEMM
  if (Nc > 0)
    gemm_bt<false><<<(Nc >> 7) * 32, 256, 0, stream>>>(e2full, k3wt, k3_b, Wcache, 4096, 512);

  float* hc = hA;
  float* hn = hB;
  for (int l = 0; l < 3; ++l) {
    hipMemsetAsync(agg, 0, (size_t)NN * 64 * 4, stream);
    if (Nc > 0)
      msg_kernel<<<(Nc + 3) / 4, 256, 0, stream>>>(hc, Wcache, ei, agg, 0, Nc);
    if (Te > 0) {
      dim3 grid(Mt128 >> 7, 4);
      k3msgG2<<<grid, 256, 0, stream>>>(e2full + (size_t)Nc * 512, k3wt, k3_b,
                                        hc, ei, agg, Nc, Te);
    }
    update_kernel<<<(NN + 3) / 4, 256, 0, stream>>>(hc, agg, deg, root, gcn_b, hn);
    float* tmp = hc; hc = hn; hn = tmp;
  }

  fc2_kernel<<<(NN + 3) / 4, 256, 0, stream>>>(hc, fc2_w, fc2_b, out);
}

// Round 11
// 863.009 us; speedup vs baseline: 1.0206x; 1.0206x over previous
//
#include <hip/hip_runtime.h>
#include <hip/hip_bf16.h>
#include <stdint.h>

#define NN 10000
#define EE 50000
#define MPAD 50176  // EE padded to multiple of 128

typedef __hip_bfloat16 bf16_t;
typedef __attribute__((ext_vector_type(8))) short bf16x8;
typedef __attribute__((ext_vector_type(4))) float f32x4;

__device__ __forceinline__ float bf2f(unsigned short u) {
  union { unsigned int i; float f; } v; v.i = ((unsigned int)u) << 16; return v.f;
}

__device__ __forceinline__ void async_load16(const void* g, void* lds) {
  __builtin_amdgcn_global_load_lds((const __attribute__((address_space(1))) uint32_t*)g,
                                   (__attribute__((address_space(3))) uint32_t*)lds,
                                   16, 0, 0);
}

#define MFMA16(a, b, c) __builtin_amdgcn_mfma_f32_16x16x32_bf16(a, b, c, 0, 0, 0)

// C[M][N] = act(A[M][K] @ Bt[N][K]^T + bias[N]); bf16 row-major, M,N mult 128, K mult 64.
// Proven r2 structure: 944 TF, MfmaUtil 42%, 0 bank conflicts. DO NOT TOUCH without A/B.
template <bool RELU>
__global__ __launch_bounds__(256, 2)
void gemm_bt(const bf16_t* __restrict__ A, const bf16_t* __restrict__ Bt,
             const float* __restrict__ bias, bf16_t* __restrict__ C,
             int N, int K) {
  __shared__ __align__(16) bf16_t As[128 * 64];
  __shared__ __align__(16) bf16_t Bs[128 * 64];

  const int t = threadIdx.x;
  const int lane = t & 63;
  const int wave = t >> 6;
  const int nt = N >> 7;
  const int bm = blockIdx.x / nt;
  const int bn = blockIdx.x % nt;
  const size_t aRowBase = (size_t)bm << 7;
  const size_t bRowBase = (size_t)bn << 7;

  const int wrBase = (wave >> 1) << 6;
  const int wcBase = (wave & 1) << 6;
  const int lo = lane & 15;
  const int hi = lane >> 4;

  f32x4 acc[4][4] = {};

  const int stg_r = t >> 3;
  const int stg_s = t & 7;
  char* AsB = (char*)As;
  char* BsB = (char*)Bs;

  const int nkt = K >> 6;
  for (int kt = 0; kt < nkt; ++kt) {
    __syncthreads();
    #pragma unroll
    for (int it = 0; it < 4; ++it) {
      const int r = (it << 5) + stg_r;
      const int ls = (stg_s ^ (r & 7)) << 3;
      async_load16(A + (aRowBase + r) * K + (kt << 6) + ls,
                   AsB + (it << 12) + (wave << 10));
      async_load16(Bt + (bRowBase + r) * K + (kt << 6) + ls,
                   BsB + (it << 12) + (wave << 10));
    }
    __syncthreads();
    #pragma unroll
    for (int ks = 0; ks < 2; ++ks) {
      bf16x8 af[4], bfr[4];
      #pragma unroll
      for (int m = 0; m < 4; ++m) {
        const int row = wrBase + (m << 4) + lo;
        const int ps = ((ks << 2) + hi) ^ (row & 7);
        af[m] = *(const bf16x8*)(AsB + (row << 7) + (ps << 4));
      }
      #pragma unroll
      for (int n = 0; n < 4; ++n) {
        const int row = wcBase + (n << 4) + lo;
        const int ps = ((ks << 2) + hi) ^ (row & 7);
        bfr[n] = *(const bf16x8*)(BsB + (row << 7) + (ps << 4));
      }
      #pragma unroll
      for (int m = 0; m < 4; ++m)
        #pragma unroll
        for (int n = 0; n < 4; ++n)
          acc[m][n] = MFMA16(af[m], bfr[n], acc[m][n]);
    }
  }

  #pragma unroll
  for (int m = 0; m < 4; ++m) {
    #pragma unroll
    for (int n = 0; n < 4; ++n) {
      const int col = (bn << 7) + wcBase + (n << 4) + lo;
      const float bv = bias[col];
      #pragma unroll
      for (int j = 0; j < 4; ++j) {
        const int row = (bm << 7) + wrBase + (m << 4) + (hi << 2) + j;
        float v = acc[m][n][j] + bv;
        if (RELU) v = fmaxf(v, 0.0f);
        C[(size_t)row * N + col] = __float2bfloat16(v);
      }
    }
  }
}

// Fused k3 GEMM + per-edge matvec + atomic scatter (r9 k3msgG, byte-identical except
// the block->(mt,s) mapping). r10 lesson: keep VGPR 60 / occ 35% (msg[2][4][4]=32,
// acc[2][4]=32 AGPR); r9 lesson vs r11: s-MAJOR mapping so during each quarter of the
// dispatch all 8 XCDs work the SAME 1MB Bt col-slice -> L2-resident Bt (r9's mt-major
// cycled each XCD through all 4MB -> 363MB re-fetch of a 32MB working set).
// Block: 64 edges (mt) x 1024 cols (s; col-tiles bn = s*8+ct, ct 0..7 of 128 cols).
// Per ct: full-K (8 kt) gemm_bt-style single-buffered loop -> acc; fold into msg regs
// (i = 2*bn + wcb is ONE h value/thread, read from LDS h-slice); bias per ct (full K).
// 4 waves 2x2: wrBase=(w>>1)*32 (m-frags 2), wcBase=(w&1)*64 (n-frags 4, o=(nf<<4)+lo).
__global__ __launch_bounds__(256, 2)
void k3msgG(const bf16_t* __restrict__ A, const bf16_t* __restrict__ Bt,
            const float* __restrict__ b3, const float* __restrict__ h,
            const int* __restrict__ ei, float* __restrict__ agg,
            int e0, int ne) {
  __shared__ __align__(16) char AsB[8192];    // [row64][slot8]*16B
  __shared__ __align__(16) char BsB[16384];   // [col128][slot8]*16B
  __shared__ __align__(16) float HL[64 * 20]; // h[row][s*16..+15], stride 20

  const int t = threadIdx.x, lane = t & 63, w = t >> 6;
  const int wrBase = (w >> 1) << 5;   // 0 or 32
  const int wcb = w & 1;              // col-half -> i parity
  const int wcBase = wcb << 6;        // 0 or 64
  const int lo = lane & 15, hi = lane >> 4;
  // s-MAJOR mapping (the one change vs r9): s = bid / nmt, mt = bid % nmt
  const int nmt = gridDim.x >> 2;
  const int s = blockIdx.x / nmt;
  const int mt = blockIdx.x - s * nmt;
  const int aRow0 = mt << 6;

  // gather h slice: thread t -> row t>>2, float4 at (t&3)*4 (cols s*16..+15)
  {
    const int row = t >> 2, c4 = (t & 3) << 2;
    const int rg = aRow0 + row;
    float4 hv = make_float4(0.0f, 0.0f, 0.0f, 0.0f);
    if (rg < ne) {
      const unsigned sv = (unsigned)ei[e0 + rg];
      if (sv < NN) hv = *(const float4*)(h + ((size_t)sv << 6) + (s << 4) + c4);
    }
    *(float4*)(HL + row * 20 + c4) = hv;
  }

  const int str = t >> 3;  // 0..31
  const int sts = t & 7;

  float msg[2][4][4] = {};  // [mf][nf][j]

  for (int ct = 0; ct < 8; ++ct) {
    const int bn = (s << 3) + ct;
    f32x4 acc[2][4] = {};
    for (int kt = 0; kt < 8; ++kt) {
      __syncthreads();
      // stage A [64 rows][64 k]: 2 loads/thread
      #pragma unroll
      for (int q = 0; q < 2; ++q) {
        const int r = str + (q << 5);
        const int ls = ((sts ^ (r & 7)) << 3);
        async_load16(A + (size_t)(aRow0 + r) * 512 + (kt << 6) + ls,
                     AsB + (q << 12) + (w << 10));
      }
      // stage B [128 cols][64 k]: 4 loads/thread
      #pragma unroll
      for (int q = 0; q < 4; ++q) {
        const int c = str + (q << 5);
        const int ls = ((sts ^ (c & 7)) << 3);
        async_load16(Bt + (size_t)((bn << 7) + c) * 512 + (kt << 6) + ls,
                     BsB + (q << 12) + (w << 10));
      }
      __syncthreads();
      #pragma unroll
      for (int ks = 0; ks < 2; ++ks) {
        bf16x8 af[2], bfr[4];
        #pragma unroll
        for (int mf = 0; mf < 2; ++mf) {
          const int row = wrBase + (mf << 4) + lo;
          const int ps = ((ks << 2) + hi) ^ (row & 7);
          af[mf] = *(const bf16x8*)(AsB + (row << 7) + (ps << 4));
        }
        #pragma unroll
        for (int nf = 0; nf < 4; ++nf) {
          const int cl = wcBase + (nf << 4) + lo;
          const int ps = ((ks << 2) + hi) ^ (cl & 7);
          bfr[nf] = *(const bf16x8*)(BsB + (cl << 7) + (ps << 4));
        }
        #pragma unroll
        for (int mf = 0; mf < 2; ++mf)
          #pragma unroll
          for (int nf = 0; nf < 4; ++nf)
            acc[mf][nf] = MFMA16(af[mf], bfr[nf], acc[mf][nf]);
      }
    }
    // fold: i = 2*bn + wcb; iloc = 2*ct + wcb; o = (nf<<4)+lo
    const int iloc = (ct << 1) + wcb;
    float bv[4];
    #pragma unroll
    for (int nf = 0; nf < 4; ++nf)
      bv[nf] = b3[(bn << 7) + wcBase + (nf << 4) + lo];
    #pragma unroll
    for (int mf = 0; mf < 2; ++mf)
      #pragma unroll
      for (int j = 0; j < 4; ++j) {
        const int row = wrBase + (mf << 4) + (hi << 2) + j;
        const float hv = HL[row * 20 + iloc];
        #pragma unroll
        for (int nf = 0; nf < 4; ++nf)
          msg[mf][nf][j] = fmaf(hv, acc[mf][nf][j] + bv[nf], msg[mf][nf][j]);
      }
  }

  // scatter: o = (nf<<4)+lo (wcb halves hold complementary i-partials for same o)
  #pragma unroll
  for (int mf = 0; mf < 2; ++mf)
    #pragma unroll
    for (int j = 0; j < 4; ++j) {
      const int rg = aRow0 + wrBase + (mf << 4) + (hi << 2) + j;
      if (rg < ne) {
        const unsigned dst = (unsigned)ei[EE + e0 + rg];
        if (dst < NN) {
          float* ag = agg + ((size_t)dst << 6);
          #pragma unroll
          for (int nf = 0; nf < 4; ++nf)
            atomicAdd(ag + (nf << 4) + lo, msg[mf][nf][j]);
        }
      }
    }
}

// wt[n*K + k] = bf16(w[k*N + n])  (transpose + cast)
__global__ void convert_t(const float* __restrict__ w, bf16_t* __restrict__ wt,
                          int K, int N) {
  int idx = blockIdx.x * 256 + threadIdx.x;
  if (idx >= K * N) return;
  int n = idx / K, k = idx - n * K;
  wt[idx] = __float2bfloat16(w[(size_t)k * N + n]);
}

__global__ void fc1_kernel(const float* __restrict__ x, const float* __restrict__ w,
                           const float* __restrict__ b, float* __restrict__ h) {
  int idx = blockIdx.x * 256 + threadIdx.x;
  if (idx >= NN * 64) return;
  int n = idx >> 6, j = idx & 63;
  h[idx] = fmaf(x[n], w[j], b[j]);
}

__global__ void deg_kernel(const int* __restrict__ ei, float* __restrict__ deg) {
  int e = blockIdx.x * 256 + threadIdx.x;
  if (e < EE) {
    unsigned d = (unsigned)ei[EE + e];
    if (d < NN) atomicAdd(&deg[d], 1.0f);
  }
}

// e1[el][0:256] = relu(attr[e0+el] @ k1_w + k1_b), zeros for rows >= ne
__global__ void k1_kernel(const float* __restrict__ attr, const float* __restrict__ w,
                          const float* __restrict__ b, bf16_t* __restrict__ e1,
                          int e0, int ne) {
  const int el = blockIdx.x;
  const int j = threadIdx.x;
  __shared__ float a[6];
  if (el < ne && j < 6) a[j] = attr[(size_t)(e0 + el) * 6 + j];
  __syncthreads();
  float v = 0.0f;
  if (el < ne) {
    v = b[j];
    #pragma unroll
    for (int i = 0; i < 6; ++i) v = fmaf(a[i], w[i * 256 + j], v);
    v = fmaxf(v, 0.0f);
  }
  e1[(size_t)el * 256 + j] = __float2bfloat16(v);
}

// per-edge matvec from cached W (bf16): msg[o] = sum_i h[src][i]*W[el][i*64+o]
__global__ __launch_bounds__(256)
void msg_kernel(const float* __restrict__ h, const bf16_t* __restrict__ W,
                const int* __restrict__ ei, float* __restrict__ agg,
                int e0, int ne) {
  const int el = blockIdx.x * 4 + (threadIdx.x >> 6);
  if (el >= ne) return;
  const int e = e0 + el;
  const int lane = threadIdx.x & 63;
  const int g = lane >> 4, c = lane & 15;
  const unsigned src = (unsigned)ei[e], dst = (unsigned)ei[EE + e];
  if (src >= NN || dst >= NN) return;
  const float hv = h[src * 64 + lane];
  const unsigned short* We = (const unsigned short*)(W + (size_t)el * 4096);
  float a0 = 0, a1 = 0, a2 = 0, a3 = 0;
  #pragma unroll
  for (int i0 = 0; i0 < 64; i0 += 4) {
    const int i = i0 + g;
    const float hs = __shfl(hv, i);
    ushort4 wv = *(const ushort4*)(We + i * 64 + c * 4);
    a0 = fmaf(hs, bf2f(wv.x), a0);
    a1 = fmaf(hs, bf2f(wv.y), a1);
    a2 = fmaf(hs, bf2f(wv.z), a2);
    a3 = fmaf(hs, bf2f(wv.w), a3);
  }
  a0 += __shfl_xor(a0, 16); a0 += __shfl_xor(a0, 32);
  a1 += __shfl_xor(a1, 16); a1 += __shfl_xor(a1, 32);
  a2 += __shfl_xor(a2, 16); a2 += __shfl_xor(a2, 32);
  a3 += __shfl_xor(a3, 16); a3 += __shfl_xor(a3, 32);
  if (g == 0) {
    float* ag = agg + (size_t)dst * 64 + c * 4;
    atomicAdd(ag + 0, a0);
    atomicAdd(ag + 1, a1);
    atomicAdd(ag + 2, a2);
    atomicAdd(ag + 3, a3);
  }
}

// h_new = relu(agg/deg + h @ root + gcn_b)
__global__ __launch_bounds__(256)
void update_kernel(const float* __restrict__ h, const float* __restrict__ agg,
                   const float* __restrict__ deg, const float* __restrict__ root,
                   const float* __restrict__ gb, float* __restrict__ hn) {
  const int n = blockIdx.x * 4 + (threadIdx.x >> 6);
  if (n >= NN) return;
  const int lane = threadIdx.x & 63;
  const float hv = h[n * 64 + lane];
  float acc = 0.0f;
  #pragma unroll
  for (int i = 0; i < 64; ++i)
    acc = fmaf(__shfl(hv, i), root[i * 64 + lane], acc);
  const float d = fmaxf(deg[n], 1.0f);
  const float v = agg[n * 64 + lane] / d + acc + gb[lane];
  hn[n * 64 + lane] = fmaxf(v, 0.0f);
}

__global__ __launch_bounds__(256)
void fc2_kernel(const float* __restrict__ h, const float* __restrict__ w,
                const float* __restrict__ b, float* __restrict__ out) {
  const int n = blockIdx.x * 4 + (threadIdx.x >> 6);
  if (n >= NN) return;
  const int lane = threadIdx.x & 63;
  float v = h[n * 64 + lane] * w[lane];
  #pragma unroll
  for (int off = 32; off > 0; off >>= 1) v += __shfl_xor(v, off);
  if (lane == 0) out[n] = v + b[0];
}

extern "C" void kernel_launch(void* const* d_in, const int* in_sizes, int n_in,
                              void* d_out, int out_size, void* d_ws, size_t ws_size,
                              hipStream_t stream) {
  const float* x     = (const float*)d_in[0];
  const int*   ei    = (const int*)d_in[1];
  const float* attr  = (const float*)d_in[2];
  const float* fc1_w = (const float*)d_in[3];
  const float* fc1_b = (const float*)d_in[4];
  const float* k1_w  = (const float*)d_in[5];
  const float* k1_b  = (const float*)d_in[6];
  const float* k2_w  = (const float*)d_in[7];
  const float* k2_b  = (const float*)d_in[8];
  const float* k3_w  = (const float*)d_in[9];
  const float* k3_b  = (const float*)d_in[10];
  const float* root  = (const float*)d_in[11];
  const float* gcn_b = (const float*)d_in[12];
  const float* fc2_w = (const float*)d_in[13];
  const float* fc2_b = (const float*)d_in[14];
  float* out = (float*)d_out;
  (void)in_sizes; (void)n_in; (void)out_size;

  char* ws = (char*)d_ws;
  size_t off = 0;
  auto take = [&](size_t bytes) -> char* {
    char* p = ws + off;
    off += (bytes + 255) & ~(size_t)255;
    return p;
  };
  // fixed small buffers (~12.2 MB)
  bf16_t* k2wt = (bf16_t*)take((size_t)512 * 256 * 2);
  bf16_t* k3wt = (bf16_t*)take((size_t)4096 * 512 * 2);
  float*  hA   = (float*)take((size_t)NN * 64 * 4);
  float*  hB   = (float*)take((size_t)NN * 64 * 4);
  float*  agg  = (float*)take((size_t)NN * 64 * 4);
  float*  deg  = (float*)take((size_t)NN * 4);

  // e2 for all edges (51.4 MB); remaining region = e1 (transient) then Wcache
  bf16_t* e2full = (bf16_t*)take((size_t)MPAD * 512 * 2);
  size_t rem = (ws_size > off + 1024) ? ws_size - off - 1024 : 0;
  int Nc = (int)((rem / 8192) / 128) * 128;  // cached edges, mult of 128
  if (Nc > 49920) Nc = 49920;  // keep Te >= 80 (never let Te < 0)
  if (Nc < 0) Nc = 0;
  size_t e1B = (size_t)MPAD * 256 * 2;  // 25.7 MB
  size_t regionB = (size_t)Nc * 8192;
  if (regionB < e1B) regionB = e1B;
  char* region = take(regionB);
  bf16_t* Wcache = (bf16_t*)region;
  bf16_t* e1 = (bf16_t*)region;  // dead after k2; overwritten by Wcache fill

  const int Te = EE - Nc;               // tail edges (fused per layer)
  const int Mt64 = (Te + 63) & ~63;     // padded to 64 (Nc + Mt64 <= MPAD)

  // weight transposes + casts
  convert_t<<<(512 * 256 + 255) / 256, 256, 0, stream>>>(k2_w, k2wt, 256, 512);
  convert_t<<<(4096 * 512 + 255) / 256, 256, 0, stream>>>(k3_w, k3wt, 512, 4096);

  // h0 = x @ fc1_w + fc1_b
  fc1_kernel<<<(NN * 64 + 255) / 256, 256, 0, stream>>>(x, fc1_w, fc1_b, hA);

  // in-degree
  hipMemsetAsync(deg, 0, NN * 4, stream);
  deg_kernel<<<(EE + 255) / 256, 256, 0, stream>>>(ei, deg);

  // edge MLP front (full): k1 -> e1, k2 -> e2full
  k1_kernel<<<MPAD, 256, 0, stream>>>(attr, k1_w, k1_b, e1, 0, EE);
  gemm_bt<true><<<(MPAD >> 7) * 4, 256, 0, stream>>>(e1, k2wt, k2_b, e2full, 512, 256);

  // W cache fill (h-independent, once): proven 944-TF GEMM
  if (Nc > 0)
    gemm_bt<false><<<(Nc >> 7) * 32, 256, 0, stream>>>(e2full, k3wt, k3_b, Wcache, 4096, 512);

  float* hc = hA;
  float* hn = hB;
  for (int l = 0; l < 3; ++l) {
    hipMemsetAsync(agg, 0, (size_t)NN * 64 * 4, stream);
    if (Nc > 0)
      msg_kernel<<<(Nc + 3) / 4, 256, 0, stream>>>(hc, Wcache, ei, agg, 0, Nc);
    if (Te > 0)
      k3msgG<<<(Mt64 >> 6) * 4, 256, 0, stream>>>(e2full + (size_t)Nc * 512, k3wt, k3_b,
                                                  hc, ei, agg, Nc, Te);
    update_kernel<<<(NN + 3) / 4, 256, 0, stream>>>(hc, agg, deg, root, gcn_b, hn);
    float* tmp = hc; hc = hn; hn = tmp;
  }

  fc2_kernel<<<(NN + 3) / 4, 256, 0, stream>>>(hc, fc2_w, fc2_b, out);
}

// Round 12
// 796.040 us; speedup vs baseline: 1.1065x; 1.0841x over previous
//
#include <hip/hip_runtime.h>
#include <hip/hip_bf16.h>
#include <stdint.h>

#define NN 10000
#define EE 50000
#define MPAD 50176  // EE padded to multiple of 128

typedef __hip_bfloat16 bf16_t;
typedef __attribute__((ext_vector_type(8))) short bf16x8;
typedef __attribute__((ext_vector_type(4))) float f32x4;

__device__ __forceinline__ float bf2f(unsigned short u) {
  union { unsigned int i; float f; } v; v.i = ((unsigned int)u) << 16; return v.f;
}

__device__ __forceinline__ void async_load16(const void* g, void* lds) {
  __builtin_amdgcn_global_load_lds((const __attribute__((address_space(1))) uint32_t*)g,
                                   (__attribute__((address_space(3))) uint32_t*)lds,
                                   16, 0, 0);
}

#define MFMA16(a, b, c) __builtin_amdgcn_mfma_f32_16x16x32_bf16(a, b, c, 0, 0, 0)

// C[M][N] = act(A[M][K] @ Bt[N][K]^T + bias[N]); bf16 row-major, M,N mult 128, K mult 64.
// Proven r2 structure: 944 TF, MfmaUtil 42%, 0 bank conflicts. DO NOT TOUCH without A/B.
template <bool RELU>
__global__ __launch_bounds__(256, 2)
void gemm_bt(const bf16_t* __restrict__ A, const bf16_t* __restrict__ Bt,
             const float* __restrict__ bias, bf16_t* __restrict__ C,
             int N, int K) {
  __shared__ __align__(16) bf16_t As[128 * 64];
  __shared__ __align__(16) bf16_t Bs[128 * 64];

  const int t = threadIdx.x;
  const int lane = t & 63;
  const int wave = t >> 6;
  const int nt = N >> 7;
  const int bm = blockIdx.x / nt;
  const int bn = blockIdx.x % nt;
  const size_t aRowBase = (size_t)bm << 7;
  const size_t bRowBase = (size_t)bn << 7;

  const int wrBase = (wave >> 1) << 6;
  const int wcBase = (wave & 1) << 6;
  const int lo = lane & 15;
  const int hi = lane >> 4;

  f32x4 acc[4][4] = {};

  const int stg_r = t >> 3;
  const int stg_s = t & 7;
  char* AsB = (char*)As;
  char* BsB = (char*)Bs;

  const int nkt = K >> 6;
  for (int kt = 0; kt < nkt; ++kt) {
    __syncthreads();
    #pragma unroll
    for (int it = 0; it < 4; ++it) {
      const int r = (it << 5) + stg_r;
      const int ls = (stg_s ^ (r & 7)) << 3;
      async_load16(A + (aRowBase + r) * K + (kt << 6) + ls,
                   AsB + (it << 12) + (wave << 10));
      async_load16(Bt + (bRowBase + r) * K + (kt << 6) + ls,
                   BsB + (it << 12) + (wave << 10));
    }
    __syncthreads();
    #pragma unroll
    for (int ks = 0; ks < 2; ++ks) {
      bf16x8 af[4], bfr[4];
      #pragma unroll
      for (int m = 0; m < 4; ++m) {
        const int row = wrBase + (m << 4) + lo;
        const int ps = ((ks << 2) + hi) ^ (row & 7);
        af[m] = *(const bf16x8*)(AsB + (row << 7) + (ps << 4));
      }
      #pragma unroll
      for (int n = 0; n < 4; ++n) {
        const int row = wcBase + (n << 4) + lo;
        const int ps = ((ks << 2) + hi) ^ (row & 7);
        bfr[n] = *(const bf16x8*)(BsB + (row << 7) + (ps << 4));
      }
      #pragma unroll
      for (int m = 0; m < 4; ++m)
        #pragma unroll
        for (int n = 0; n < 4; ++n)
          acc[m][n] = MFMA16(af[m], bfr[n], acc[m][n]);
    }
  }

  #pragma unroll
  for (int m = 0; m < 4; ++m) {
    #pragma unroll
    for (int n = 0; n < 4; ++n) {
      const int col = (bn << 7) + wcBase + (n << 4) + lo;
      const float bv = bias[col];
      #pragma unroll
      for (int j = 0; j < 4; ++j) {
        const int row = (bm << 7) + wrBase + (m << 4) + (hi << 2) + j;
        float v = acc[m][n][j] + bv;
        if (RELU) v = fmaxf(v, 0.0f);
        C[(size_t)row * N + col] = __float2bfloat16(v);
      }
    }
  }
}

// Merged per-layer dispatch: fused k3+msg tail blocks (bid%5==0) interleaved with
// cached-W msg blocks (other 4/5). r11 lesson: fused kernel is latency-bound with
// HBM at 7% and MFMA pipe stalling on stage drains; msg blocks are pure-memory with
// MFMA idle -> co-resident blocks overlap complementary pipes (m114 mechanism).
// Fused body = r11 k3msgG verbatim (s-major col mapping, FETCH 55MB proven).
// Msg body = msg_kernel verbatim on Wcache edges [0, min(Nc, 16*nFused)).
__global__ __launch_bounds__(256, 2)
void layer_fused(const bf16_t* __restrict__ A, const bf16_t* __restrict__ Bt,
                 const float* __restrict__ b3, const float* __restrict__ h,
                 const bf16_t* __restrict__ Wc, const int* __restrict__ ei,
                 float* __restrict__ agg, int e0, int ne, int nmt, int nMsgE) {
  __shared__ __align__(16) char AsB[8192];    // [row64][slot8]*16B
  __shared__ __align__(16) char BsB[16384];   // [col128][slot8]*16B
  __shared__ __align__(16) float HL[64 * 20]; // h[row][s*16..+15], stride 20

  const int bid = blockIdx.x;
  const int t = threadIdx.x, lane = t & 63, w = t >> 6;

  if (bid % 5 != 0) {
    // ---- cached-W msg block (4 edges/block) ----
    const int mid = bid - bid / 5 - 1;
    const int el = (mid << 2) + (t >> 6);
    if (el >= nMsgE) return;
    const int g = lane >> 4, c = lane & 15;
    const unsigned src = (unsigned)ei[el], dst = (unsigned)ei[EE + el];
    if (src >= NN || dst >= NN) return;
    const float hv = h[src * 64 + lane];
    const unsigned short* We = (const unsigned short*)(Wc + (size_t)el * 4096);
    float a0 = 0, a1 = 0, a2 = 0, a3 = 0;
    #pragma unroll
    for (int i0 = 0; i0 < 64; i0 += 4) {
      const int i = i0 + g;
      const float hs = __shfl(hv, i);
      ushort4 wv = *(const ushort4*)(We + i * 64 + c * 4);
      a0 = fmaf(hs, bf2f(wv.x), a0);
      a1 = fmaf(hs, bf2f(wv.y), a1);
      a2 = fmaf(hs, bf2f(wv.z), a2);
      a3 = fmaf(hs, bf2f(wv.w), a3);
    }
    a0 += __shfl_xor(a0, 16); a0 += __shfl_xor(a0, 32);
    a1 += __shfl_xor(a1, 16); a1 += __shfl_xor(a1, 32);
    a2 += __shfl_xor(a2, 16); a2 += __shfl_xor(a2, 32);
    a3 += __shfl_xor(a3, 16); a3 += __shfl_xor(a3, 32);
    if (g == 0) {
      float* ag = agg + (size_t)dst * 64 + c * 4;
      atomicAdd(ag + 0, a0);
      atomicAdd(ag + 1, a1);
      atomicAdd(ag + 2, a2);
      atomicAdd(ag + 3, a3);
    }
    return;
  }

  // ---- fused k3-GEMM + msg tail block (r11 k3msgG body) ----
  const int fid = bid / 5;
  const int wrBase = (w >> 1) << 5;   // 0 or 32
  const int wcb = w & 1;              // col-half -> i parity
  const int wcBase = wcb << 6;        // 0 or 64
  const int lo = lane & 15, hi = lane >> 4;
  const int s = fid / nmt;            // s-major (r11: Bt L2-resident per phase)
  const int mt = fid - s * nmt;
  const int aRow0 = mt << 6;

  // gather h slice: thread t -> row t>>2, float4 at (t&3)*4 (cols s*16..+15)
  {
    const int row = t >> 2, c4 = (t & 3) << 2;
    const int rg = aRow0 + row;
    float4 hv = make_float4(0.0f, 0.0f, 0.0f, 0.0f);
    if (rg < ne) {
      const unsigned sv = (unsigned)ei[e0 + rg];
      if (sv < NN) hv = *(const float4*)(h + ((size_t)sv << 6) + (s << 4) + c4);
    }
    *(float4*)(HL + row * 20 + c4) = hv;
  }

  const int str = t >> 3;  // 0..31
  const int sts = t & 7;

  float msg[2][4][4] = {};  // [mf][nf][j]

  for (int ct = 0; ct < 8; ++ct) {
    const int bn = (s << 3) + ct;
    f32x4 acc[2][4] = {};
    for (int kt = 0; kt < 8; ++kt) {
      __syncthreads();
      #pragma unroll
      for (int q = 0; q < 2; ++q) {
        const int r = str + (q << 5);
        const int ls = ((sts ^ (r & 7)) << 3);
        async_load16(A + (size_t)(aRow0 + r) * 512 + (kt << 6) + ls,
                     AsB + (q << 12) + (w << 10));
      }
      #pragma unroll
      for (int q = 0; q < 4; ++q) {
        const int c = str + (q << 5);
        const int ls = ((sts ^ (c & 7)) << 3);
        async_load16(Bt + (size_t)((bn << 7) + c) * 512 + (kt << 6) + ls,
                     BsB + (q << 12) + (w << 10));
      }
      __syncthreads();
      #pragma unroll
      for (int ks = 0; ks < 2; ++ks) {
        bf16x8 af[2], bfr[4];
        #pragma unroll
        for (int mf = 0; mf < 2; ++mf) {
          const int row = wrBase + (mf << 4) + lo;
          const int ps = ((ks << 2) + hi) ^ (row & 7);
          af[mf] = *(const bf16x8*)(AsB + (row << 7) + (ps << 4));
        }
        #pragma unroll
        for (int nf = 0; nf < 4; ++nf) {
          const int cl = wcBase + (nf << 4) + lo;
          const int ps = ((ks << 2) + hi) ^ (cl & 7);
          bfr[nf] = *(const bf16x8*)(BsB + (cl << 7) + (ps << 4));
        }
        #pragma unroll
        for (int mf = 0; mf < 2; ++mf)
          #pragma unroll
          for (int nf = 0; nf < 4; ++nf)
            acc[mf][nf] = MFMA16(af[mf], bfr[nf], acc[mf][nf]);
      }
    }
    const int iloc = (ct << 1) + wcb;
    float bv[4];
    #pragma unroll
    for (int nf = 0; nf < 4; ++nf)
      bv[nf] = b3[(bn << 7) + wcBase + (nf << 4) + lo];
    #pragma unroll
    for (int mf = 0; mf < 2; ++mf)
      #pragma unroll
      for (int j = 0; j < 4; ++j) {
        const int row = wrBase + (mf << 4) + (hi << 2) + j;
        const float hv = HL[row * 20 + iloc];
        #pragma unroll
        for (int nf = 0; nf < 4; ++nf)
          msg[mf][nf][j] = fmaf(hv, acc[mf][nf][j] + bv[nf], msg[mf][nf][j]);
      }
  }

  #pragma unroll
  for (int mf = 0; mf < 2; ++mf)
    #pragma unroll
    for (int j = 0; j < 4; ++j) {
      const int rg = aRow0 + wrBase + (mf << 4) + (hi << 2) + j;
      if (rg < ne) {
        const unsigned dst = (unsigned)ei[EE + e0 + rg];
        if (dst < NN) {
          float* ag = agg + ((size_t)dst << 6);
          #pragma unroll
          for (int nf = 0; nf < 4; ++nf)
            atomicAdd(ag + (nf << 4) + lo, msg[mf][nf][j]);
        }
      }
    }
}

// wt[n*K + k] = bf16(w[k*N + n])  (transpose + cast)
__global__ void convert_t(const float* __restrict__ w, bf16_t* __restrict__ wt,
                          int K, int N) {
  int idx = blockIdx.x * 256 + threadIdx.x;
  if (idx >= K * N) return;
  int n = idx / K, k = idx - n * K;
  wt[idx] = __float2bfloat16(w[(size_t)k * N + n]);
}

__global__ void fc1_kernel(const float* __restrict__ x, const float* __restrict__ w,
                           const float* __restrict__ b, float* __restrict__ h) {
  int idx = blockIdx.x * 256 + threadIdx.x;
  if (idx >= NN * 64) return;
  int n = idx >> 6, j = idx & 63;
  h[idx] = fmaf(x[n], w[j], b[j]);
}

__global__ void deg_kernel(const int* __restrict__ ei, float* __restrict__ deg) {
  int e = blockIdx.x * 256 + threadIdx.x;
  if (e < EE) {
    unsigned d = (unsigned)ei[EE + e];
    if (d < NN) atomicAdd(&deg[d], 1.0f);
  }
}

// e1[el][0:256] = relu(attr[e0+el] @ k1_w + k1_b), zeros for rows >= ne
__global__ void k1_kernel(const float* __restrict__ attr, const float* __restrict__ w,
                          const float* __restrict__ b, bf16_t* __restrict__ e1,
                          int e0, int ne) {
  const int el = blockIdx.x;
  const int j = threadIdx.x;
  __shared__ float a[6];
  if (el < ne && j < 6) a[j] = attr[(size_t)(e0 + el) * 6 + j];
  __syncthreads();
  float v = 0.0f;
  if (el < ne) {
    v = b[j];
    #pragma unroll
    for (int i = 0; i < 6; ++i) v = fmaf(a[i], w[i * 256 + j], v);
    v = fmaxf(v, 0.0f);
  }
  e1[(size_t)el * 256 + j] = __float2bfloat16(v);
}

// per-edge matvec from cached W (bf16): msg[o] = sum_i h[src][i]*W[el][i*64+o]
__global__ __launch_bounds__(256)
void msg_kernel(const float* __restrict__ h, const bf16_t* __restrict__ W,
                const int* __restrict__ ei, float* __restrict__ agg,
                int e0, int ne) {
  const int el = blockIdx.x * 4 + (threadIdx.x >> 6);
  if (el >= ne) return;
  const int e = e0 + el;
  const int lane = threadIdx.x & 63;
  const int g = lane >> 4, c = lane & 15;
  const unsigned src = (unsigned)ei[e], dst = (unsigned)ei[EE + e];
  if (src >= NN || dst >= NN) return;
  const float hv = h[src * 64 + lane];
  const unsigned short* We = (const unsigned short*)(W + (size_t)el * 4096);
  float a0 = 0, a1 = 0, a2 = 0, a3 = 0;
  #pragma unroll
  for (int i0 = 0; i0 < 64; i0 += 4) {
    const int i = i0 + g;
    const float hs = __shfl(hv, i);
    ushort4 wv = *(const ushort4*)(We + i * 64 + c * 4);
    a0 = fmaf(hs, bf2f(wv.x), a0);
    a1 = fmaf(hs, bf2f(wv.y), a1);
    a2 = fmaf(hs, bf2f(wv.z), a2);
    a3 = fmaf(hs, bf2f(wv.w), a3);
  }
  a0 += __shfl_xor(a0, 16); a0 += __shfl_xor(a0, 32);
  a1 += __shfl_xor(a1, 16); a1 += __shfl_xor(a1, 32);
  a2 += __shfl_xor(a2, 16); a2 += __shfl_xor(a2, 32);
  a3 += __shfl_xor(a3, 16); a3 += __shfl_xor(a3, 32);
  if (g == 0) {
    float* ag = agg + (size_t)dst * 64 + c * 4;
    atomicAdd(ag + 0, a0);
    atomicAdd(ag + 1, a1);
    atomicAdd(ag + 2, a2);
    atomicAdd(ag + 3, a3);
  }
}

// h_new = relu(agg/deg + h @ root + gcn_b)
__global__ __launch_bounds__(256)
void update_kernel(const float* __restrict__ h, const float* __restrict__ agg,
                   const float* __restrict__ deg, const float* __restrict__ root,
                   const float* __restrict__ gb, float* __restrict__ hn) {
  const int n = blockIdx.x * 4 + (threadIdx.x >> 6);
  if (n >= NN) return;
  const int lane = threadIdx.x & 63;
  const float hv = h[n * 64 + lane];
  float acc = 0.0f;
  #pragma unroll
  for (int i = 0; i < 64; ++i)
    acc = fmaf(__shfl(hv, i), root[i * 64 + lane], acc);
  const float d = fmaxf(deg[n], 1.0f);
  const float v = agg[n * 64 + lane] / d + acc + gb[lane];
  hn[n * 64 + lane] = fmaxf(v, 0.0f);
}

__global__ __launch_bounds__(256)
void fc2_kernel(const float* __restrict__ h, const float* __restrict__ w,
                const float* __restrict__ b, float* __restrict__ out) {
  const int n = blockIdx.x * 4 + (threadIdx.x >> 6);
  if (n >= NN) return;
  const int lane = threadIdx.x & 63;
  float v = h[n * 64 + lane] * w[lane];
  #pragma unroll
  for (int off = 32; off > 0; off >>= 1) v += __shfl_xor(v, off);
  if (lane == 0) out[n] = v + b[0];
}

extern "C" void kernel_launch(void* const* d_in, const int* in_sizes, int n_in,
                              void* d_out, int out_size, void* d_ws, size_t ws_size,
                              hipStream_t stream) {
  const float* x     = (const float*)d_in[0];
  const int*   ei    = (const int*)d_in[1];
  const float* attr  = (const float*)d_in[2];
  const float* fc1_w = (const float*)d_in[3];
  const float* fc1_b = (const float*)d_in[4];
  const float* k1_w  = (const float*)d_in[5];
  const float* k1_b  = (const float*)d_in[6];
  const float* k2_w  = (const float*)d_in[7];
  const float* k2_b  = (const float*)d_in[8];
  const float* k3_w  = (const float*)d_in[9];
  const float* k3_b  = (const float*)d_in[10];
  const float* root  = (const float*)d_in[11];
  const float* gcn_b = (const float*)d_in[12];
  const float* fc2_w = (const float*)d_in[13];
  const float* fc2_b = (const float*)d_in[14];
  float* out = (float*)d_out;
  (void)in_sizes; (void)n_in; (void)out_size;

  char* ws = (char*)d_ws;
  size_t off = 0;
  auto take = [&](size_t bytes) -> char* {
    char* p = ws + off;
    off += (bytes + 255) & ~(size_t)255;
    return p;
  };
  // fixed small buffers (~12.2 MB)
  bf16_t* k2wt = (bf16_t*)take((size_t)512 * 256 * 2);
  bf16_t* k3wt = (bf16_t*)take((size_t)4096 * 512 * 2);
  float*  hA   = (float*)take((size_t)NN * 64 * 4);
  float*  hB   = (float*)take((size_t)NN * 64 * 4);
  float*  agg  = (float*)take((size_t)NN * 64 * 4);
  float*  deg  = (float*)take((size_t)NN * 4);

  // e2 for all edges (51.4 MB); remaining region = e1 (transient) then Wcache
  bf16_t* e2full = (bf16_t*)take((size_t)MPAD * 512 * 2);
  size_t rem = (ws_size > off + 1024) ? ws_size - off - 1024 : 0;
  int Nc = (int)((rem / 8192) / 128) * 128;  // cached edges, mult of 128
  if (Nc > 49920) Nc = 49920;  // keep Te >= 80 (never let Te < 0)
  if (Nc < 0) Nc = 0;
  size_t e1B = (size_t)MPAD * 256 * 2;  // 25.7 MB
  size_t regionB = (size_t)Nc * 8192;
  if (regionB < e1B) regionB = e1B;
  char* region = take(regionB);
  bf16_t* Wcache = (bf16_t*)region;
  bf16_t* e1 = (bf16_t*)region;  // dead after k2; overwritten by Wcache fill

  const int Te = EE - Nc;               // tail edges (fused per layer)
  const int Mt64 = (Te + 63) & ~63;     // padded to 64 (Nc + Mt64 <= MPAD)
  const int nmt = Mt64 >> 6;
  const int nFused = nmt * 4;           // fused blocks (s-major: fid = s*nmt + mt)
  const int msgCap = nFused << 4;       // cached edges coverable by 4*nFused blocks
  const int NcIn = (Nc < msgCap) ? Nc : msgCap;   // handled inside layer_fused
  const int NcOut = Nc - NcIn;                    // leftover (separate dispatch)

  // weight transposes + casts
  convert_t<<<(512 * 256 + 255) / 256, 256, 0, stream>>>(k2_w, k2wt, 256, 512);
  convert_t<<<(4096 * 512 + 255) / 256, 256, 0, stream>>>(k3_w, k3wt, 512, 4096);

  // h0 = x @ fc1_w + fc1_b
  fc1_kernel<<<(NN * 64 + 255) / 256, 256, 0, stream>>>(x, fc1_w, fc1_b, hA);

  // in-degree
  hipMemsetAsync(deg, 0, NN * 4, stream);
  deg_kernel<<<(EE + 255) / 256, 256, 0, stream>>>(ei, deg);

  // edge MLP front (full): k1 -> e1, k2 -> e2full
  k1_kernel<<<MPAD, 256, 0, stream>>>(attr, k1_w, k1_b, e1, 0, EE);
  gemm_bt<true><<<(MPAD >> 7) * 4, 256, 0, stream>>>(e1, k2wt, k2_b, e2full, 512, 256);

  // W cache fill (h-independent, once): proven 944-TF GEMM
  if (Nc > 0)
    gemm_bt<false><<<(Nc >> 7) * 32, 256, 0, stream>>>(e2full, k3wt, k3_b, Wcache, 4096, 512);

  float* hc = hA;
  float* hn = hB;
  for (int l = 0; l < 3; ++l) {
    hipMemsetAsync(agg, 0, (size_t)NN * 64 * 4, stream);
    if (Te > 0) {
      // merged dispatch: fused tail blocks (1/5) interleaved with cached-msg blocks (4/5)
      layer_fused<<<nFused * 5, 256, 0, stream>>>(e2full + (size_t)Nc * 512, k3wt, k3_b,
                                                  hc, Wcache, ei, agg, Nc, Te, nmt, NcIn);
      if (NcOut > 0)
        msg_kernel<<<(NcOut + 3) / 4, 256, 0, stream>>>(hc, Wcache, ei, agg, NcIn, NcOut);
    } else if (Nc > 0) {
      msg_kernel<<<(Nc + 3) / 4, 256, 0, stream>>>(hc, Wcache, ei, agg, 0, Nc);
    }
    update_kernel<<<(NN + 3) / 4, 256, 0, stream>>>(hc, agg, deg, root, gcn_b, hn);
    float* tmp = hc; hc = hn; hn = tmp;
  }

  fc2_kernel<<<(NN + 3) / 4, 256, 0, stream>>>(hc, fc2_w, fc2_b, out);
}